// Round 8
// baseline (682.964 us; speedup 1.0000x reference)
//
#include <hip/hip_runtime.h>

#define NT 128      // num tags
#define SEQ 1024    // sequence length
#define NB 256      // batch

typedef _Float16 half2v __attribute__((ext_vector_type(2)));

// One DPP max step on the VALU pipe (no DS/lgkmcnt involvement).
#define DPP_MAX_STEP(x, ctrl)                                                   \
    fmaxf((x), __builtin_bit_cast(float, __builtin_amdgcn_update_dpp(           \
        __builtin_bit_cast(int, (x)), __builtin_bit_cast(int, (x)),             \
        (ctrl), 0xf, 0xf, false)))

__device__ __forceinline__ float wave_max_dpp(float x) {
    x = DPP_MAX_STEP(x, 0x111);   // row_shr:1
    x = DPP_MAX_STEP(x, 0x112);   // row_shr:2
    x = DPP_MAX_STEP(x, 0x114);   // row_shr:4
    x = DPP_MAX_STEP(x, 0x118);   // row_shr:8
    x = DPP_MAX_STEP(x, 0x142);   // row_bcast:15
    x = DPP_MAX_STEP(x, 0x143);   // row_bcast:31
    return __builtin_bit_cast(float, __builtin_amdgcn_readlane(
        __builtin_bit_cast(int, x), 63));
}

// lane[i^1] via DPP quad_perm [1,0,3,2] (ctrl 0xB1) -- VALU, exact.
__device__ __forceinline__ float swap1_dpp(float x) {
    return __builtin_bit_cast(float, __builtin_amdgcn_update_dpp(
        0, __builtin_bit_cast(int, x), 0xB1, 0xf, 0xf, true));
}

// One scan step, 2-wave cooperative version. Lane owns ONE column c = tid;
// the full 128-long dot is lane-local (64 fdot2, 4 independent 16-deep
// accumulator chains) -- no cross-lane dot combine. P lives in LDS as packed
// f16 pairs (64 uints), double-buffered (BUF); broadcast same-address
// ds_read_b128 x16 per wave. One __syncthreads per step (ping-pong: reads of
// BUF and writes of BUF^1 both precede the barrier; write-after-read on BUF^1
// is protected by the PREVIOUS barrier). The 2 per-wave maxes ride the same
// barrier; every thread derives the same global mx/inv/offadd.
#define CRF_STEP(RC, RN, MC, DO_PRE, K, BUF)                                     \
    {                                                                            \
        float mcur = MC;                                                         \
        if (DO_PRE) { RC = emp[(K) * NT]; MC = mpp[K]; }                         \
        float eRN = __expf(RN);          /* hoisted off the post-barrier path */ \
        const uint4* p4 = (const uint4*)&p_lds[BUF][0];                          \
        float A0=0.f, A1=0.f, A2=0.f, A3=0.f;                                    \
        _Pragma("unroll")                                                        \
        for (int qi = 0; qi < 16; ++qi) {                                        \
            uint4 q = p4[qi];                                                    \
            A0 = __builtin_amdgcn_fdot2(__builtin_bit_cast(half2v, q.x),         \
                                        E[4*qi+0], A0, false);                   \
            A1 = __builtin_amdgcn_fdot2(__builtin_bit_cast(half2v, q.y),         \
                                        E[4*qi+1], A1, false);                   \
            A2 = __builtin_amdgcn_fdot2(__builtin_bit_cast(half2v, q.z),         \
                                        E[4*qi+2], A2, false);                   \
            A3 = __builtin_amdgcn_fdot2(__builtin_bit_cast(half2v, q.w),         \
                                        E[4*qi+3], A3, false);                   \
        }                                                                        \
        float sv = (A0 + A1) + (A2 + A3);                                        \
        float v = sv * ex;                                                       \
        if (mcur > 0.0f) { cur = v; offset += offadd; }                          \
        float curo = swap1_dpp(cur);     /* partner column c^1 for f16 pack */   \
        if ((c & 1) == 0)                                                        \
            p_lds[(BUF)^1][c >> 1] = __builtin_bit_cast(unsigned int,            \
                __builtin_amdgcn_cvt_pkrtz(cur, curo));                          \
        float wm = wave_max_dpp(cur);                                            \
        if (l == 0) wmax[(BUF)^1][w] = wm;                                       \
        __syncthreads();                                                         \
        float2 wv = *(const float2*)&wmax[(BUF)^1][0];                           \
        mx = fmaxf(wv.x, wv.y);                                                  \
        inv = __builtin_amdgcn_rcpf(256.0f * mx);                                \
        offadd = __logf(mx) + 5.545177444479562f;                                \
        ex = eRN * inv;                                                          \
    }

// TWO WAVES per batch element. 256 blocks x 128 threads. The wave-count
// ladder (1 wave: 1258 cy/step issue-bound; 4: 1012; 8: 1235) has its
// untested minimum at 2: fewest waves that still split the dot issue
// (64 fdot2/lane), narrowest barrier, per-wave fixed overhead paid twice
// not 4x, and zero cross-lane dot combines. Same total DS traffic as the
// 4-wave version. E (prob domain f16 pairs, column c) is 64 VGPRs.
__global__ __launch_bounds__(128, 1) void crf_scan_kernel(
    const float* __restrict__ emissions,    // [B,S,T]
    const float* __restrict__ masks,        // [B,S]
    const int*   __restrict__ tags,         // [B,S]
    const float* __restrict__ transitions,  // [T,T] (log domain)
    const float* __restrict__ start_t,      // [T]
    const float* __restrict__ end_t,        // [T]
    float* __restrict__ out_per_batch)      // [B]
{
    const int b   = blockIdx.x;
    const int tid = threadIdx.x;
    const int w   = tid >> 6;     // wave 0..1
    const int l   = tid & 63;     // lane 0..63
    const int c   = tid;          // owned output column 0..127

    __shared__ __align__(16) unsigned int p_lds[2][64]; // packed f16 P pairs
    __shared__ __align__(16) float        wmax[2][2];   // per-wave maxes
    __shared__ float redA[2], redB[2], redC[2];         // epilogue reductions
    __shared__ float msk_s[SEQ];

    // ---- E column c: rows 2r, 2r+1 packed as f16 pairs (prob domain). ----
    // Loads are coalesced across lanes (lane dim = column = contiguous).
    half2v E[64];
    #pragma unroll
    for (int r = 0; r < 64; ++r) {
        float ea = transitions[(2*r    ) * NT + c];
        float ob = transitions[(2*r + 1) * NT + c];
        E[r] = half2v{(_Float16)__expf(ea), (_Float16)__expf(ob)};
    }

    for (int s = tid; s < SEQ; s += 128)
        msk_s[s] = masks[b * SEQ + s];

    // ---- init: P = exp(start), offset = 0 ----
    float cur = __expf(start_t[c]);
    float offset = 0.0f;

    {
        float curo = swap1_dpp(cur);
        if ((c & 1) == 0)
            p_lds[0][c >> 1] = __builtin_bit_cast(unsigned int,
                __builtin_amdgcn_cvt_pkrtz(cur, curo));
        float wm = wave_max_dpp(cur);
        if (l == 0) wmax[0][w] = wm;
    }
    __syncthreads();

    float2 wv0 = *(const float2*)&wmax[0][0];
    float mx   = fmaxf(wv0.x, wv0.y);
    float inv  = __builtin_amdgcn_rcpf(256.0f * mx);
    float offadd = __logf(mx) + 5.545177444479562f;   // log(256*mx)

    const float* eb  = emissions + (size_t)b * SEQ * NT;
    const float* mkp = masks + b * SEQ;

    // depth-4 rings: slot k holds em/mask for step s with s&3==k (scalar)
    float ring0 = eb[(size_t)0 * NT + c];
    float ring1 = eb[(size_t)1 * NT + c];
    float ring2 = eb[(size_t)2 * NT + c];
    float ring3 = eb[(size_t)3 * NT + c];
    float mr0 = mkp[0], mr1 = mkp[1], mr2 = mkp[2], mr3 = mkp[3];

    float ex = __expf(ring0) * inv;

    const float* emp = eb + 4 * NT + c;   // em[s+4] for s=0
    const float* mpp = mkp + 4;

    // main loop: steps 0..1019, unrolled x4 (ring slots static; BUF = s&1)
    for (int it = 0; it < (SEQ - 4) / 4; ++it) {
        CRF_STEP(ring0, ring1, mr0, true, 0, 0)
        CRF_STEP(ring1, ring2, mr1, true, 1, 1)
        CRF_STEP(ring2, ring3, mr2, true, 2, 0)
        CRF_STEP(ring3, ring0, mr3, true, 3, 1)
        emp += 4 * NT;
        mpp += 4;
    }
    // tail: steps 1020..1023 (no prefetch)
    CRF_STEP(ring0, ring1, mr0, false, 0, 0)
    CRF_STEP(ring1, ring2, mr1, false, 0, 1)
    CRF_STEP(ring2, ring3, mr2, false, 0, 0)
    CRF_STEP(ring3, ring3, mr3, false, 0, 1)

    // ---- log_z = offset + log( sum_j P_j * exp(end_j) ) ----
    float term = cur * __expf(end_t[c]);
    #pragma unroll
    for (int off = 32; off; off >>= 1)
        term += __shfl_xor(term, off);
    if (l == 0) redA[w] = term;

    // ---- gold-path score (128 threads, 8 s-iters each) ----
    const int tbase = b * SEQ;
    float sc = 0.0f, sm = 0.0f;
    for (int s = tid; s < SEQ; s += 128) {
        float m = msk_s[s];
        sm += m;
        if (s < SEQ - 1) {
            int tg  = tags[tbase + s];
            int tg1 = tags[tbase + s + 1];
            sc += eb[(size_t)s * NT + tg] * m;
            sc += transitions[tg * NT + tg1] * msk_s[s + 1];
        }
    }
    #pragma unroll
    for (int off = 32; off; off >>= 1) {
        sc += __shfl_xor(sc, off);
        sm += __shfl_xor(sm, off);
    }
    if (l == 0) { redB[w] = sc; redC[w] = sm; }
    __syncthreads();

    if (tid == 0) {
        float term_t = redA[0] + redA[1];
        float log_z  = offset + __logf(term_t);
        float sct    = redB[0] + redB[1];
        float smt    = redC[0] + redC[1];
        int tg0 = tags[tbase];
        int tgl = tags[tbase + SEQ - 1];
        sct += start_t[tg0];
        int last_ix = (int)fmaxf(smt - 1.0f, 0.0f);
        float ml = msk_s[SEQ - 1];
        sct += eb[(size_t)last_ix * NT + tgl] * ml;
        sct += end_t[tgl] * ml;
        out_per_batch[b] = log_z - sct;
    }
}

// mean over batch -> scalar output
__global__ void crf_reduce_kernel(const float* __restrict__ pb, float* __restrict__ out)
{
    float v = pb[threadIdx.x];   // 256 threads, one per batch
    #pragma unroll
    for (int off = 32; off; off >>= 1)
        v += __shfl_xor(v, off);
    __shared__ float s4[4];
    if ((threadIdx.x & 63) == 0) s4[threadIdx.x >> 6] = v;
    __syncthreads();
    if (threadIdx.x == 0)
        out[0] = (s4[0] + s4[1] + s4[2] + s4[3]) * (1.0f / 256.0f);
}

extern "C" void kernel_launch(void* const* d_in, const int* in_sizes, int n_in,
                              void* d_out, int out_size, void* d_ws, size_t ws_size,
                              hipStream_t stream) {
    const float* emissions   = (const float*)d_in[0];
    const float* masks       = (const float*)d_in[1];
    const int*   tags        = (const int*)  d_in[2];
    const float* transitions = (const float*)d_in[3];
    const float* start_t     = (const float*)d_in[4];
    const float* end_t       = (const float*)d_in[5];
    float* per_batch = (float*)d_ws;

    crf_scan_kernel<<<NB, 128, 0, stream>>>(emissions, masks, tags, transitions,
                                            start_t, end_t, per_batch);
    crf_reduce_kernel<<<1, 256, 0, stream>>>(per_batch, (float*)d_out);
}

// Round 9
// 620.865 us; speedup vs baseline: 1.1000x; 1.1000x over previous
//
#include <hip/hip_runtime.h>

#define NT 128      // num tags
#define SEQ 1024    // sequence length
#define NB 256      // batch

typedef _Float16 half2v __attribute__((ext_vector_type(2)));

// One DPP max step on the VALU pipe (no DS/lgkmcnt involvement).
#define DPP_MAX_STEP(x, ctrl)                                                   \
    fmaxf((x), __builtin_bit_cast(float, __builtin_amdgcn_update_dpp(           \
        __builtin_bit_cast(int, (x)), __builtin_bit_cast(int, (x)),             \
        (ctrl), 0xf, 0xf, false)))

__device__ __forceinline__ float wave_max_dpp(float x) {
    x = DPP_MAX_STEP(x, 0x111);   // row_shr:1
    x = DPP_MAX_STEP(x, 0x112);   // row_shr:2
    x = DPP_MAX_STEP(x, 0x114);   // row_shr:4
    x = DPP_MAX_STEP(x, 0x118);   // row_shr:8
    x = DPP_MAX_STEP(x, 0x142);   // row_bcast:15
    x = DPP_MAX_STEP(x, 0x143);   // row_bcast:31
    return __builtin_bit_cast(float, __builtin_amdgcn_readlane(
        __builtin_bit_cast(int, x), 63));
}

// lane[i] + lane[i^32] on the VALU pipe (v_permlane32_swap_b32, gfx950).
__device__ __forceinline__ float cross32_add(float x) {
    float a = x, b = x;
    asm volatile("v_permlane32_swap_b32 %0, %1" : "+v"(a), "+v"(b));
    return a + b;
}

// lane[i] + lane[i^16] on the VALU pipe (v_permlane16_swap_b32, gfx950).
// Validated bit-exact in the round-5 kernel (absmax 0).
__device__ __forceinline__ float cross16_add(float x) {
    float a = x, b = x;
    asm volatile("v_permlane16_swap_b32 %0, %1" : "+v"(a), "+v"(b));
    return a + b;
}

// Packed f16 max (2 lanes of f16 per u32). Scalar values only (no arrays ->
// no scratch risk).
__device__ __forceinline__ unsigned int pk_max_u(unsigned int a, unsigned int b) {
    unsigned int r;
    asm("v_pk_max_f16 %0, %1, %2" : "=v"(r) : "v"(a), "v"(b));
    return r;
}

// One scan step, 4-wave / K-quartered version.
// Wave w owns 32 columns as 16 PAIRS: lane cl=l&15 owns cols (32w+2cl,
// 32w+2cl+1); kq=l>>4 selects the K-quarter rows [32kq,32kq+32).
// DS traffic per step per wave: 4 ds_read_b128 (quarter of packed P) +
// 1 ds_write_b32 (kq==0 lanes write the new packed pairs). No wmax
// exchange: the global max is recomputed by EVERY wave from the identical
// f16 P data it just read (pk_max tree + DPP wave max -> bitwise-identical
// mx in all waves). The rescale invariant (offset += log(256*mx),
// inv = rcp(256*mx)) is exact for any uniform scale, so f16-rounded mx
// only perturbs rounding. One __syncthreads per step (ping-pong buffers).
#define CRF_STEP(RC, MC, DO_PRE, K, BUF)                                         \
    {                                                                            \
        float2 emv = RC;                                                         \
        float mcur = MC;                                                         \
        if (DO_PRE) { RC = *(const float2*)(emp + (K) * NT); MC = mpp[K]; }      \
        float e2x = __expf(emv.x), e2y = __expf(emv.y);                          \
        const uint4* p4 = (const uint4*)&p_lds[BUF][16 * kq];                    \
        uint4 q0 = p4[0], q1 = p4[1], q2 = p4[2], q3 = p4[3];                    \
        /* global max of P from the just-read f16 data (no LDS exchange) */      \
        unsigned int m0 = pk_max_u(pk_max_u(q0.x, q0.y), pk_max_u(q0.z, q0.w));  \
        unsigned int m1 = pk_max_u(pk_max_u(q1.x, q1.y), pk_max_u(q1.z, q1.w));  \
        unsigned int m2 = pk_max_u(pk_max_u(q2.x, q2.y), pk_max_u(q2.z, q2.w));  \
        unsigned int m3 = pk_max_u(pk_max_u(q3.x, q3.y), pk_max_u(q3.z, q3.w));  \
        unsigned int mm = pk_max_u(pk_max_u(m0, m1), pk_max_u(m2, m3));          \
        half2v mh = __builtin_bit_cast(half2v, mm);                              \
        float mx = wave_max_dpp(fmaxf((float)mh.x, (float)mh.y));                \
        float inv = __builtin_amdgcn_rcpf(256.0f * mx);                          \
        float offadd = __logf(mx) + 5.545177444479562f;                          \
        float ex0 = e2x * inv, ex1 = e2y * inv;                                  \
        float A0=0.f,A1=0.f,A2=0.f,A3=0.f,B0=0.f,B1=0.f,B2=0.f,B3=0.f;           \
        A0 = __builtin_amdgcn_fdot2(__builtin_bit_cast(half2v,q0.x), E0[0],  A0, false); \
        B0 = __builtin_amdgcn_fdot2(__builtin_bit_cast(half2v,q0.x), E1[0],  B0, false); \
        A1 = __builtin_amdgcn_fdot2(__builtin_bit_cast(half2v,q0.y), E0[1],  A1, false); \
        B1 = __builtin_amdgcn_fdot2(__builtin_bit_cast(half2v,q0.y), E1[1],  B1, false); \
        A2 = __builtin_amdgcn_fdot2(__builtin_bit_cast(half2v,q0.z), E0[2],  A2, false); \
        B2 = __builtin_amdgcn_fdot2(__builtin_bit_cast(half2v,q0.z), E1[2],  B2, false); \
        A3 = __builtin_amdgcn_fdot2(__builtin_bit_cast(half2v,q0.w), E0[3],  A3, false); \
        B3 = __builtin_amdgcn_fdot2(__builtin_bit_cast(half2v,q0.w), E1[3],  B3, false); \
        A0 = __builtin_amdgcn_fdot2(__builtin_bit_cast(half2v,q1.x), E0[4],  A0, false); \
        B0 = __builtin_amdgcn_fdot2(__builtin_bit_cast(half2v,q1.x), E1[4],  B0, false); \
        A1 = __builtin_amdgcn_fdot2(__builtin_bit_cast(half2v,q1.y), E0[5],  A1, false); \
        B1 = __builtin_amdgcn_fdot2(__builtin_bit_cast(half2v,q1.y), E1[5],  B1, false); \
        A2 = __builtin_amdgcn_fdot2(__builtin_bit_cast(half2v,q1.z), E0[6],  A2, false); \
        B2 = __builtin_amdgcn_fdot2(__builtin_bit_cast(half2v,q1.z), E1[6],  B2, false); \
        A3 = __builtin_amdgcn_fdot2(__builtin_bit_cast(half2v,q1.w), E0[7],  A3, false); \
        B3 = __builtin_amdgcn_fdot2(__builtin_bit_cast(half2v,q1.w), E1[7],  B3, false); \
        A0 = __builtin_amdgcn_fdot2(__builtin_bit_cast(half2v,q2.x), E0[8],  A0, false); \
        B0 = __builtin_amdgcn_fdot2(__builtin_bit_cast(half2v,q2.x), E1[8],  B0, false); \
        A1 = __builtin_amdgcn_fdot2(__builtin_bit_cast(half2v,q2.y), E0[9],  A1, false); \
        B1 = __builtin_amdgcn_fdot2(__builtin_bit_cast(half2v,q2.y), E1[9],  B1, false); \
        A2 = __builtin_amdgcn_fdot2(__builtin_bit_cast(half2v,q2.z), E0[10], A2, false); \
        B2 = __builtin_amdgcn_fdot2(__builtin_bit_cast(half2v,q2.z), E1[10], B2, false); \
        A3 = __builtin_amdgcn_fdot2(__builtin_bit_cast(half2v,q2.w), E0[11], A3, false); \
        B3 = __builtin_amdgcn_fdot2(__builtin_bit_cast(half2v,q2.w), E1[11], B3, false); \
        A0 = __builtin_amdgcn_fdot2(__builtin_bit_cast(half2v,q3.x), E0[12], A0, false); \
        B0 = __builtin_amdgcn_fdot2(__builtin_bit_cast(half2v,q3.x), E1[12], B0, false); \
        A1 = __builtin_amdgcn_fdot2(__builtin_bit_cast(half2v,q3.y), E0[13], A1, false); \
        B1 = __builtin_amdgcn_fdot2(__builtin_bit_cast(half2v,q3.y), E1[13], B1, false); \
        A2 = __builtin_amdgcn_fdot2(__builtin_bit_cast(half2v,q3.z), E0[14], A2, false); \
        B2 = __builtin_amdgcn_fdot2(__builtin_bit_cast(half2v,q3.z), E1[14], B2, false); \
        A3 = __builtin_amdgcn_fdot2(__builtin_bit_cast(half2v,q3.w), E0[15], A3, false); \
        B3 = __builtin_amdgcn_fdot2(__builtin_bit_cast(half2v,q3.w), E1[15], B3, false); \
        float sA = cross32_add(cross16_add((A0 + A1) + (A2 + A3)));              \
        float sB = cross32_add(cross16_add((B0 + B1) + (B2 + B3)));              \
        float v0 = sA * ex0;                                                     \
        float v1 = sB * ex1;                                                     \
        if (mcur > 0.0f) { cur0 = v0; cur1 = v1; offset += offadd; }             \
        if (kq == 0)                                                             \
            p_lds[(BUF)^1][16*w + cl] = __builtin_bit_cast(unsigned int,         \
                __builtin_amdgcn_cvt_pkrtz(cur0, cur1));                         \
        __syncthreads();                                                         \
    }

// FOUR WAVES per batch element. 256 blocks x 256 threads. The round-1..8
// wave ladder showed the binding resource is the CU's single DS pipe
// (~44 DS instrs/step in the round-4 kernel ~= the unexplained ~550 cy).
// This version cuts DS to 20 instrs/step: K-quartered reads (4 b128/wave),
// one b32 write/wave, and NO wmax exchange (max recomputed redundantly
// per-wave from the identical f16 P data via v_pk_max_f16 + DPP).
__global__ __launch_bounds__(256, 1) void crf_scan_kernel(
    const float* __restrict__ emissions,    // [B,S,T]
    const float* __restrict__ masks,        // [B,S]
    const int*   __restrict__ tags,         // [B,S]
    const float* __restrict__ transitions,  // [T,T] (log domain)
    const float* __restrict__ start_t,      // [T]
    const float* __restrict__ end_t,        // [T]
    float* __restrict__ out_per_batch)      // [B]
{
    const int b   = blockIdx.x;
    const int tid = threadIdx.x;
    const int w   = tid >> 6;       // wave 0..3
    const int l   = tid & 63;       // lane 0..63
    const int cl  = l & 15;         // column-pair index within wave
    const int kq  = l >> 4;         // K-quarter 0..3
    const int c0  = 32 * w + 2 * cl;
    const int c1  = c0 + 1;
    const int i0  = 32 * kq;        // this lane's K range start

    __shared__ __align__(16) unsigned int p_lds[2][64]; // packed f16 P pairs
    __shared__ float redA[4], redB[4], redC[4];         // epilogue reductions
    __shared__ float msk_s[SEQ];

    // ---- E fragment: rows i0+2j, i0+2j+1 of cols c0,c1 (prob domain) ----
    half2v E0[16], E1[16];
    #pragma unroll
    for (int j = 0; j < 16; ++j) {
        float2 ta = *(const float2*)&transitions[(i0 + 2*j    ) * NT + c0];
        float2 tb = *(const float2*)&transitions[(i0 + 2*j + 1) * NT + c0];
        E0[j] = half2v{(_Float16)__expf(ta.x), (_Float16)__expf(tb.x)};
        E1[j] = half2v{(_Float16)__expf(ta.y), (_Float16)__expf(tb.y)};
    }

    for (int s = tid; s < SEQ; s += 256)
        msk_s[s] = masks[b * SEQ + s];

    // ---- init: P = exp(start), offset = 0 ----
    float cur0 = __expf(start_t[c0]);
    float cur1 = __expf(start_t[c1]);
    float offset = 0.0f;

    if (kq == 0)
        p_lds[0][16*w + cl] = __builtin_bit_cast(unsigned int,
            __builtin_amdgcn_cvt_pkrtz(cur0, cur1));
    __syncthreads();

    const float* eb  = emissions + (size_t)b * SEQ * NT;
    const float* mkp = masks + b * SEQ;

    // depth-4 rings: slot k holds em pair/mask for step s with s&3==k
    float2 ring0 = *(const float2*)&eb[(size_t)0 * NT + c0];
    float2 ring1 = *(const float2*)&eb[(size_t)1 * NT + c0];
    float2 ring2 = *(const float2*)&eb[(size_t)2 * NT + c0];
    float2 ring3 = *(const float2*)&eb[(size_t)3 * NT + c0];
    float  mr0 = mkp[0], mr1 = mkp[1], mr2 = mkp[2], mr3 = mkp[3];

    const float* emp = eb + 4 * NT + c0;   // em[s+4] pair for s=0
    const float* mpp = mkp + 4;

    // main loop: steps 0..1019, unrolled x4 (ring slots static; BUF = s&1)
    for (int it = 0; it < (SEQ - 4) / 4; ++it) {
        CRF_STEP(ring0, mr0, true, 0, 0)
        CRF_STEP(ring1, mr1, true, 1, 1)
        CRF_STEP(ring2, mr2, true, 2, 0)
        CRF_STEP(ring3, mr3, true, 3, 1)
        emp += 4 * NT;
        mpp += 4;
    }
    // tail: steps 1020..1023 (no prefetch)
    CRF_STEP(ring0, mr0, false, 0, 0)
    CRF_STEP(ring1, mr1, false, 0, 1)
    CRF_STEP(ring2, mr2, false, 0, 0)
    CRF_STEP(ring3, mr3, false, 0, 1)

    // ---- log_z = offset + log( sum_j P_j * exp(end_j) ) ----
    // cur0/cur1 replicated across the 4 K-quarter groups; count kq==0 only.
    float term = (kq == 0)
               ? cur0 * __expf(end_t[c0]) + cur1 * __expf(end_t[c1]) : 0.0f;
    #pragma unroll
    for (int off = 32; off; off >>= 1)
        term += __shfl_xor(term, off);
    if (l == 0) redA[w] = term;

    // ---- gold-path score (256 threads, 4 s-iters each) ----
    const int tbase = b * SEQ;
    float sc = 0.0f, sm = 0.0f;
    for (int s = tid; s < SEQ; s += 256) {
        float m = msk_s[s];
        sm += m;
        if (s < SEQ - 1) {
            int tg  = tags[tbase + s];
            int tg1 = tags[tbase + s + 1];
            sc += eb[(size_t)s * NT + tg] * m;
            sc += transitions[tg * NT + tg1] * msk_s[s + 1];
        }
    }
    #pragma unroll
    for (int off = 32; off; off >>= 1) {
        sc += __shfl_xor(sc, off);
        sm += __shfl_xor(sm, off);
    }
    if (l == 0) { redB[w] = sc; redC[w] = sm; }
    __syncthreads();

    if (tid == 0) {
        float term_t = (redA[0] + redA[1]) + (redA[2] + redA[3]);
        float log_z  = offset + __logf(term_t);
        float sct    = (redB[0] + redB[1]) + (redB[2] + redB[3]);
        float smt    = (redC[0] + redC[1]) + (redC[2] + redC[3]);
        int tg0 = tags[tbase];
        int tgl = tags[tbase + SEQ - 1];
        sct += start_t[tg0];
        int last_ix = (int)fmaxf(smt - 1.0f, 0.0f);
        float ml = msk_s[SEQ - 1];
        sct += eb[(size_t)last_ix * NT + tgl] * ml;
        sct += end_t[tgl] * ml;
        out_per_batch[b] = log_z - sct;
    }
}

// mean over batch -> scalar output
__global__ void crf_reduce_kernel(const float* __restrict__ pb, float* __restrict__ out)
{
    float v = pb[threadIdx.x];   // 256 threads, one per batch
    #pragma unroll
    for (int off = 32; off; off >>= 1)
        v += __shfl_xor(v, off);
    __shared__ float s4[4];
    if ((threadIdx.x & 63) == 0) s4[threadIdx.x >> 6] = v;
    __syncthreads();
    if (threadIdx.x == 0)
        out[0] = (s4[0] + s4[1] + s4[2] + s4[3]) * (1.0f / 256.0f);
}

extern "C" void kernel_launch(void* const* d_in, const int* in_sizes, int n_in,
                              void* d_out, int out_size, void* d_ws, size_t ws_size,
                              hipStream_t stream) {
    const float* emissions   = (const float*)d_in[0];
    const float* masks       = (const float*)d_in[1];
    const int*   tags        = (const int*)  d_in[2];
    const float* transitions = (const float*)d_in[3];
    const float* start_t     = (const float*)d_in[4];
    const float* end_t       = (const float*)d_in[5];
    float* per_batch = (float*)d_ws;

    crf_scan_kernel<<<NB, 256, 0, stream>>>(emissions, masks, tags, transitions,
                                            start_t, end_t, per_batch);
    crf_reduce_kernel<<<1, 256, 0, stream>>>(per_batch, (float*)d_out);
}

// Round 10
// 558.373 us; speedup vs baseline: 1.2231x; 1.1119x over previous
//
#include <hip/hip_runtime.h>

#define NT 128      // num tags
#define SEQ 1024    // sequence length
#define NB 256      // batch

typedef _Float16 half2v __attribute__((ext_vector_type(2)));

// One DPP max step on the VALU pipe (no DS/lgkmcnt involvement).
#define DPP_MAX_STEP(x, ctrl)                                                   \
    fmaxf((x), __builtin_bit_cast(float, __builtin_amdgcn_update_dpp(           \
        __builtin_bit_cast(int, (x)), __builtin_bit_cast(int, (x)),             \
        (ctrl), 0xf, 0xf, false)))

__device__ __forceinline__ float wave_max_dpp(float x) {
    x = DPP_MAX_STEP(x, 0x111);   // row_shr:1
    x = DPP_MAX_STEP(x, 0x112);   // row_shr:2
    x = DPP_MAX_STEP(x, 0x114);   // row_shr:4
    x = DPP_MAX_STEP(x, 0x118);   // row_shr:8
    x = DPP_MAX_STEP(x, 0x142);   // row_bcast:15
    x = DPP_MAX_STEP(x, 0x143);   // row_bcast:31
    return __builtin_bit_cast(float, __builtin_amdgcn_readlane(
        __builtin_bit_cast(int, x), 63));
}

// lane[i] + lane[i^32] on the VALU pipe (v_permlane32_swap_b32, gfx950).
// With a=b=x, after the swap a+b == x[i&31] + x[(i&31)+32] in every lane.
__device__ __forceinline__ float cross32_add(float x) {
    float a = x, b = x;
    asm volatile("v_permlane32_swap_b32 %0, %1" : "+v"(a), "+v"(b));
    return a + b;
}

// lane[i^1] via DPP quad_perm [1,0,3,2] (ctrl 0xB1) -- VALU, exact.
__device__ __forceinline__ float swap1_dpp(float x) {
    return __builtin_bit_cast(float, __builtin_amdgcn_update_dpp(
        0, __builtin_bit_cast(int, x), 0xB1, 0xf, 0xf, true));
}

// One scan step, 4-wave cooperative version.
// Wave w owns columns [32w,32w+32); lane: col c=32w+(l&31), K-half ih=l>>5.
// P lives in LDS as packed f16 pairs (64 uints), double-buffered (BUF).
// One __syncthreads per step: reads of buffer BUF precede the barrier, the
// next step's writes target BUF^1 only after it (ping-pong, no 2nd barrier).
// All shuffle traffic (K-half combine, pack-partner exchange, wave max) is
// VALU (permlane/DPP); DS pipe carries only the cross-wave P/wmax exchange.
//
// NOTE (session ledger): this exact structure is the verified optimum of the
// R0-R9 exploration. Falsified alternatives: lgkm-only barrier (R3/R7 flat:
// ring prefetches land before the barrier, vmcnt drain is free), 2 waves
// (R8 +27%), 8 waves (R5 +22%), f32 pk_fma dots (R6: compiler spills E to
// scratch, +98%), per-wave redundant f16 max w/o wmax exchange (R9: wrong
// numerics + slower). The ~1000 cy/step cost is the barrier rendezvous +
// LDS turnaround + dependent dot/renorm chain, each shown inelastic.
#define CRF_STEP(RC, RN, MC, DO_PRE, K, BUF)                                     \
    {                                                                            \
        float mcur = MC;                                                         \
        if (DO_PRE) { RC = emp[(K) * NT]; MC = mpp[K]; }                         \
        float eRN = __expf(RN);          /* hoisted off the post-barrier path */ \
        const uint4* p4 = (const uint4*)&p_lds[BUF][ih * 32];                    \
        float A0=0.f, A1=0.f, A2=0.f, A3=0.f;                                    \
        _Pragma("unroll")                                                        \
        for (int qi = 0; qi < 8; ++qi) {                                         \
            uint4 q = p4[qi];                                                    \
            A0 = __builtin_amdgcn_fdot2(__builtin_bit_cast(half2v, q.x),         \
                                        E[4*qi+0], A0, false);                   \
            A1 = __builtin_amdgcn_fdot2(__builtin_bit_cast(half2v, q.y),         \
                                        E[4*qi+1], A1, false);                   \
            A2 = __builtin_amdgcn_fdot2(__builtin_bit_cast(half2v, q.z),         \
                                        E[4*qi+2], A2, false);                   \
            A3 = __builtin_amdgcn_fdot2(__builtin_bit_cast(half2v, q.w),         \
                                        E[4*qi+3], A3, false);                   \
        }                                                                        \
        float sv = cross32_add((A0 + A1) + (A2 + A3));                           \
        float v = sv * ex;                                                       \
        if (mcur > 0.0f) { cur = v; offset += offadd; }                          \
        float curo = swap1_dpp(cur);     /* partner column for f16 pack */       \
        if (ih == 0 && (cl & 1) == 0)                                            \
            p_lds[(BUF)^1][16*w + (cl >> 1)] = __builtin_bit_cast(unsigned int,  \
                __builtin_amdgcn_cvt_pkrtz(cur, curo));                          \
        float wm = wave_max_dpp(cur);                                            \
        if (l == 0) wmax[(BUF)^1][w] = wm;                                       \
        __syncthreads();                                                         \
        float4 wv = *(const float4*)&wmax[(BUF)^1][0];                           \
        mx = fmaxf(fmaxf(wv.x, wv.y), fmaxf(wv.z, wv.w));                        \
        inv = __builtin_amdgcn_rcpf(256.0f * mx);                                \
        offadd = __logf(mx) + 5.545177444479562f;                                \
        ex = eRN * inv;                                                          \
    }

// FOUR WAVES per batch element (one per SIMD of a CU). 256 blocks x 256
// threads. The 128x128 matvec is split 4 ways; P and the per-wave maxes are
// exchanged through double-buffered LDS with one __syncthreads per step.
__global__ __launch_bounds__(256, 1) void crf_scan_kernel(
    const float* __restrict__ emissions,    // [B,S,T]
    const float* __restrict__ masks,        // [B,S]
    const int*   __restrict__ tags,         // [B,S]
    const float* __restrict__ transitions,  // [T,T] (log domain)
    const float* __restrict__ start_t,      // [T]
    const float* __restrict__ end_t,        // [T]
    float* __restrict__ out_per_batch)      // [B]
{
    const int b   = blockIdx.x;
    const int tid = threadIdx.x;
    const int w   = tid >> 6;     // wave 0..3
    const int l   = tid & 63;     // lane 0..63
    const int cl  = l & 31;       // column within wave
    const int ih  = l >> 5;       // which half of the i (row) range
    const int c   = 32 * w + cl;  // owned output column
    const int i0  = 64 * ih;      // start of this lane's i range

    __shared__ __align__(16) unsigned int p_lds[2][64]; // packed f16 P pairs
    __shared__ __align__(16) float        wmax[2][4];   // per-wave maxes
    __shared__ float redA[4], redB[4], redC[4];         // epilogue reductions
    __shared__ float msk_s[SEQ];

    // ---- E fragment: rows i0+2r, i0+2r+1 of column c, prob domain f16 ----
    half2v E[32];
    #pragma unroll
    for (int r = 0; r < 32; ++r) {
        float ea = transitions[(i0 + 2*r    ) * NT + c];
        float ob = transitions[(i0 + 2*r + 1) * NT + c];
        E[r] = half2v{(_Float16)__expf(ea), (_Float16)__expf(ob)};
    }

    for (int s = tid; s < SEQ; s += 256)
        msk_s[s] = masks[b * SEQ + s];

    // ---- init: P = exp(start), offset = 0 ----
    float cur = __expf(start_t[c]);
    float offset = 0.0f;

    {
        float curo = swap1_dpp(cur);
        if (ih == 0 && (cl & 1) == 0)
            p_lds[0][16*w + (cl >> 1)] = __builtin_bit_cast(unsigned int,
                __builtin_amdgcn_cvt_pkrtz(cur, curo));
        float wm = wave_max_dpp(cur);
        if (l == 0) wmax[0][w] = wm;
    }
    __syncthreads();

    float4 wv0 = *(const float4*)&wmax[0][0];
    float mx   = fmaxf(fmaxf(wv0.x, wv0.y), fmaxf(wv0.z, wv0.w));
    float inv  = __builtin_amdgcn_rcpf(256.0f * mx);
    float offadd = __logf(mx) + 5.545177444479562f;   // log(256*mx)

    const float* eb  = emissions + (size_t)b * SEQ * NT;
    const float* mkp = masks + b * SEQ;

    // depth-4 rings: slot k holds em/mask for step s with s&3==k (scalar)
    float ring0 = eb[(size_t)0 * NT + c];
    float ring1 = eb[(size_t)1 * NT + c];
    float ring2 = eb[(size_t)2 * NT + c];
    float ring3 = eb[(size_t)3 * NT + c];
    float mr0 = mkp[0], mr1 = mkp[1], mr2 = mkp[2], mr3 = mkp[3];

    float ex = __expf(ring0) * inv;

    const float* emp = eb + 4 * NT + c;   // em[s+4] for s=0
    const float* mpp = mkp + 4;

    // main loop: steps 0..1019, unrolled x4 (ring slots static; BUF = s&1)
    for (int it = 0; it < (SEQ - 4) / 4; ++it) {
        CRF_STEP(ring0, ring1, mr0, true, 0, 0)
        CRF_STEP(ring1, ring2, mr1, true, 1, 1)
        CRF_STEP(ring2, ring3, mr2, true, 2, 0)
        CRF_STEP(ring3, ring0, mr3, true, 3, 1)
        emp += 4 * NT;
        mpp += 4;
    }
    // tail: steps 1020..1023 (no prefetch)
    CRF_STEP(ring0, ring1, mr0, false, 0, 0)
    CRF_STEP(ring1, ring2, mr1, false, 0, 1)
    CRF_STEP(ring2, ring3, mr2, false, 0, 0)
    CRF_STEP(ring3, ring3, mr3, false, 0, 1)

    // ---- log_z = offset + log( sum_j P_j * exp(end_j) ) ----
    float term = (ih == 0) ? cur * __expf(end_t[c]) : 0.0f;
    #pragma unroll
    for (int off = 32; off; off >>= 1)
        term += __shfl_xor(term, off);
    if (l == 0) redA[w] = term;

    // ---- gold-path score (256 threads, 4 s-iters each) ----
    const int tbase = b * SEQ;
    float sc = 0.0f, sm = 0.0f;
    for (int s = tid; s < SEQ; s += 256) {
        float m = msk_s[s];
        sm += m;
        if (s < SEQ - 1) {
            int tg  = tags[tbase + s];
            int tg1 = tags[tbase + s + 1];
            sc += eb[(size_t)s * NT + tg] * m;
            sc += transitions[tg * NT + tg1] * msk_s[s + 1];
        }
    }
    #pragma unroll
    for (int off = 32; off; off >>= 1) {
        sc += __shfl_xor(sc, off);
        sm += __shfl_xor(sm, off);
    }
    if (l == 0) { redB[w] = sc; redC[w] = sm; }
    __syncthreads();

    if (tid == 0) {
        float term_t = (redA[0] + redA[1]) + (redA[2] + redA[3]);
        float log_z  = offset + __logf(term_t);
        float sct    = (redB[0] + redB[1]) + (redB[2] + redB[3]);
        float smt    = (redC[0] + redC[1]) + (redC[2] + redC[3]);
        int tg0 = tags[tbase];
        int tgl = tags[tbase + SEQ - 1];
        sct += start_t[tg0];
        int last_ix = (int)fmaxf(smt - 1.0f, 0.0f);
        float ml = msk_s[SEQ - 1];
        sct += eb[(size_t)last_ix * NT + tgl] * ml;
        sct += end_t[tgl] * ml;
        out_per_batch[b] = log_z - sct;
    }
}

// mean over batch -> scalar output
__global__ void crf_reduce_kernel(const float* __restrict__ pb, float* __restrict__ out)
{
    float v = pb[threadIdx.x];   // 256 threads, one per batch
    #pragma unroll
    for (int off = 32; off; off >>= 1)
        v += __shfl_xor(v, off);
    __shared__ float s4[4];
    if ((threadIdx.x & 63) == 0) s4[threadIdx.x >> 6] = v;
    __syncthreads();
    if (threadIdx.x == 0)
        out[0] = (s4[0] + s4[1] + s4[2] + s4[3]) * (1.0f / 256.0f);
}

extern "C" void kernel_launch(void* const* d_in, const int* in_sizes, int n_in,
                              void* d_out, int out_size, void* d_ws, size_t ws_size,
                              hipStream_t stream) {
    const float* emissions   = (const float*)d_in[0];
    const float* masks       = (const float*)d_in[1];
    const int*   tags        = (const int*)  d_in[2];
    const float* transitions = (const float*)d_in[3];
    const float* start_t     = (const float*)d_in[4];
    const float* end_t       = (const float*)d_in[5];
    float* per_batch = (float*)d_ws;

    crf_scan_kernel<<<NB, 256, 0, stream>>>(emissions, masks, tags, transitions,
                                            start_t, end_t, per_batch);
    crf_reduce_kernel<<<1, 256, 0, stream>>>(per_batch, (float*)d_out);
}